// Round 8
// baseline (1811.760 us; speedup 1.0000x reference)
//
#include <hip/hip_runtime.h>
#include <hip/hip_bf16.h>

#define TREES_ 50
#define PER_ 2047
#define NN_ (TREES_ * PER_)      // 102350 nodes
#define NINT_ (TREES_ * 1023)    // 51150 internal nodes
#define NLEAF_ (TREES_ * 1024)   // 51200 leaves

typedef __attribute__((ext_vector_type(8))) short s8v;            // 8 bf16
typedef __attribute__((ext_vector_type(4))) float f4v;            // MFMA C/D
typedef __attribute__((ext_vector_type(4))) unsigned short u4v;   // 4 bf16

__device__ __forceinline__ unsigned short f2bf(float f) {
  union { float f; unsigned u; } v; v.f = f;
  unsigned r = v.u + 0x7FFFu + ((v.u >> 16) & 1u);   // RNE
  return (unsigned short)(r >> 16);
}
__device__ __forceinline__ float bf2f(unsigned short s) {
  union { unsigned u; float f; } v; v.u = ((unsigned)s) << 16;
  return v.f;
}
__device__ __forceinline__ float sigm(float x) { return 1.f / (1.f + __expf(-x)); }
__device__ __forceinline__ float tanh_s(float x) {
  float ax = fabsf(x);
  float e = __expf(2.f * ax);
  float t = 1.f - 2.f / (e + 1.f);
  return copysignf(t, x);
}
__device__ __forceinline__ f4v fz4() { f4v z; z[0]=0.f; z[1]=0.f; z[2]=0.f; z[3]=0.f; return z; }

#if defined(__has_builtin)
#if __has_builtin(__builtin_amdgcn_global_load_lds)
#define HAS_GLD 1
#endif
#endif
__device__ __forceinline__ void gld16(const void* g, void* l) {
#ifdef HAS_GLD
  __builtin_amdgcn_global_load_lds(
      (const __attribute__((address_space(1))) unsigned int*)g,
      (__attribute__((address_space(3))) unsigned int*)l, 16, 0, 0);
#else
  *(s8v*)l = *(const s8v*)g;
#endif
}

// bijective XCD-chunked swizzle (m204)
__device__ __forceinline__ int xcd_swz(int bid, int nwg) {
  int q = nwg >> 3, r = nwg & 7, x = bid & 7, pos = bid >> 3;
  int base = (x < r) ? x * (q + 1) : r * (q + 1) + (x - r) * q;
  return base + pos;
}

// LDS tile [256 rows][64 bf16]; logical chunk (row,c16) at swizzled byte.
// Staging writes LINEAR slot q=(row,c16s) from global chunk c16g=c16s^(row&7).
#define LDS_BYTE(row, c16) ((row) * 128 + (((c16) ^ ((row) & 7)) << 4))

// one K-step (64) of 256x256 tile, 8 waves (2M x 4N), per-wave 128x64 out
#define MFMA256(Ap, Bp)                                                       \
  _Pragma("unroll") for (int kk = 0; kk < 2; ++kk) {                          \
    s8v af[8], bf_[4];                                                        \
    _Pragma("unroll") for (int i = 0; i < 8; ++i) {                           \
      int R = wm * 128 + i * 16 + lr;                                         \
      af[i] = *(const s8v*)((const char*)(Ap) + LDS_BYTE(R, kk * 4 + lg));    \
    }                                                                         \
    _Pragma("unroll") for (int j = 0; j < 4; ++j) {                           \
      int R = wn * 64 + j * 16 + lr;                                          \
      bf_[j] = *(const s8v*)((const char*)(Bp) + LDS_BYTE(R, kk * 4 + lg));   \
    }                                                                         \
    _Pragma("unroll") for (int i = 0; i < 8; ++i)                             \
      _Pragma("unroll") for (int j = 0; j < 4; ++j)                           \
        acc[i][j] = __builtin_amdgcn_mfma_f32_16x16x32_bf16(af[i], bf_[j],    \
                                                            acc[i][j], 0, 0, 0); \
  }

// minimum 2-phase (T3 recipe): issue next-tile STAGE before computing current;
// one full __syncthreads (vmcnt0+lgkm0+barrier) per tile.
#define PIPE2(STAGEM, NT)                                          \
  STAGEM(0, 0)                                                     \
  __syncthreads();                                                 \
  {                                                                \
    int cur = 0;                                                   \
    for (int t = 0; t < (NT); ++t) {                               \
      if (t + 1 < (NT)) { STAGEM(cur ^ 1, (t + 1) * 64) }          \
      MFMA256(AsB + cur * 16384, BsB + cur * 16384)                \
      __syncthreads();                                             \
      cur ^= 1;                                                    \
    }                                                              \
  }

// ---------------- feat fp32 -> bf16 --------------------------------------
__global__ __launch_bounds__(256) void feat2bf(const float* __restrict__ feat,
                                               unsigned short* __restrict__ FB) {
  long long i = (long long)blockIdx.x * 256 + threadIdx.x;
  if (i >= (long long)NN_ * 64) return;
  const float* src = feat + i * 8;
  float4 f0 = *(const float4*)src;
  float4 f1 = *(const float4*)(src + 4);
  s8v v;
  v[0] = (short)f2bf(f0.x); v[1] = (short)f2bf(f0.y);
  v[2] = (short)f2bf(f0.z); v[3] = (short)f2bf(f0.w);
  v[4] = (short)f2bf(f1.x); v[5] = (short)f2bf(f1.y);
  v[6] = (short)f2bf(f1.z); v[7] = (short)f2bf(f1.w);
  *(s8v*)(FB + i * 8) = v;
}

// -------- weight prep --------
// WIOUB [1536][512] = W_iou ; UCAT3 [1536][1024] row n = [U_iou_l[n]|U_iou_r[n]]
// UFLR  [1024][512] row 2c=Ufl[c], 2c+1=Ufr[c] ; WFB [512][512] = W_f
__global__ __launch_bounds__(256) void prep_weights(
    const float* __restrict__ Wiou, const float* __restrict__ Ul,
    const float* __restrict__ Ur,  const float* __restrict__ Wf,
    const float* __restrict__ Ufl, const float* __restrict__ Ufr,
    unsigned short* __restrict__ WIOUB, unsigned short* __restrict__ UCAT3,
    unsigned short* __restrict__ UFLR, unsigned short* __restrict__ WFB) {
  int i = blockIdx.x * 256 + threadIdx.x;
  if (i < 1536 * 512) WIOUB[i] = f2bf(Wiou[i]);
  if (i < 1536 * 1024) {
    int r = i >> 10, c = i & 1023;
    float v = (c < 512) ? Ul[r * 512 + c] : Ur[r * 512 + (c - 512)];
    UCAT3[i] = f2bf(v);
  }
  if (i < 1024 * 512) {
    int r = i >> 9, k = i & 511;
    int c = r >> 1, s = r & 1;
    UFLR[i] = f2bf(s ? Ufr[c * 512 + k] : Ufl[c * 512 + k]);
  }
  if (i < 512 * 512) WFB[i] = f2bf(Wf[i]);
}

// ---- merged pre GEMMs (K=512, NT=8): WF | leaf-IOU | internal-XIOU ------
__global__ __launch_bounds__(512, 2) void pre_mm(
    const unsigned short* __restrict__ FB, const unsigned short* __restrict__ WFB,
    const unsigned short* __restrict__ WIOUB,
    const float* __restrict__ bfb, const float* __restrict__ biou,
    unsigned short* __restrict__ WF, unsigned short* __restrict__ LIOU,
    unsigned short* __restrict__ XIOU, int nwgA, int nwgB, int nwgC) {
  __shared__ __align__(16) unsigned short AsB[2 * 256 * 64];
  __shared__ __align__(16) unsigned short BsB[2 * 256 * 64];
  const int tid = threadIdx.x;
  const int wid = tid >> 6, lane = tid & 63;
  const int wm = wid >> 2, wn = wid & 3;
  const int lr = lane & 15, lg = lane >> 4;
  f4v acc[8][4];
#pragma unroll
  for (int i = 0; i < 8; ++i)
#pragma unroll
    for (int j = 0; j < 4; ++j) acc[i][j] = fz4();

  const unsigned short* aA[4]; const unsigned short* aB[4];
  int tm, tn, which;   // 0=WF 1=leaf 2=int
  if ((int)blockIdx.x < nwgA) {
    which = 0;
    int swz = xcd_swz(blockIdx.x, nwgA);
    tn = swz & 1; tm = swz >> 1;
  } else if ((int)blockIdx.x < nwgA + nwgB) {
    which = 1;
    int swz = xcd_swz((int)blockIdx.x - nwgA, nwgB);
    tn = swz % 6; tm = swz / 6;
  } else {
    which = 2;
    int swz = xcd_swz((int)blockIdx.x - nwgA - nwgB, nwgC);
    tn = swz % 6; tm = swz / 6;
  }
#pragma unroll
  for (int L = 0; L < 4; ++L) {
    int q = L * 512 + tid;
    int row = q >> 3, c16g = (q & 7) ^ (row & 7);
    int m = tm * 256 + row;
    int node;
    if (which == 1) {
      node = (m >> 10) * 2047 + (m & 1023);            // leaf map (exact)
    } else {
      if (m >= NINT_) m = NINT_ - 1;
      int t = (unsigned)m / 1023u;
      node = t * 2047 + 1024 + (m - t * 1023);          // internal map
    }
    aA[L] = FB + (size_t)node * 512 + c16g * 8;
    int n = tn * 256 + row;
    aB[L] = (which == 0 ? WFB : WIOUB) + (size_t)n * 512 + c16g * 8;
  }
#define STAGE_P(bb, kofs)                                         \
  _Pragma("unroll") for (int L = 0; L < 4; ++L) {                 \
    int q = L * 512 + tid;                                        \
    gld16(aA[L] + (kofs), AsB + (bb) * 16384 + q * 8);            \
    gld16(aB[L] + (kofs), BsB + (bb) * 16384 + q * 8);            \
  }
  PIPE2(STAGE_P, 8)

#pragma unroll
  for (int i = 0; i < 8; ++i)
#pragma unroll
    for (int j = 0; j < 4; ++j) {
      int n = tn * 256 + wn * 64 + j * 16 + lr;
      float bias = (which == 0) ? bfb[n] : biou[n];
#pragma unroll
      for (int r = 0; r < 4; ++r) {
        int m = tm * 256 + wm * 128 + i * 16 + lg * 4 + r;
        if (which == 0) {
          if (m < NINT_) WF[(size_t)m * 512 + n] = f2bf(acc[i][j][r] + bias);
        } else if (which == 1) {
          LIOU[(size_t)m * 1536 + n] = f2bf(acc[i][j][r] + bias);
        } else {
          if (m < NINT_) XIOU[(size_t)m * 1536 + n] = f2bf(acc[i][j][r] + bias);
        }
      }
    }
}

// ---- leaf elementwise ---------------------------------------------------
__global__ __launch_bounds__(256) void leaf_ew(
    const unsigned short* __restrict__ LIOU,
    float* __restrict__ h_out, float* __restrict__ c_out,
    unsigned short* __restrict__ HB) {
  int idx = blockIdx.x * 256 + threadIdx.x;
  int r = idx >> 7;
  int c4 = (idx & 127) << 2;
  int g = (r >> 10) * 2047 + (r & 1023);
  const unsigned short* pr = LIOU + (size_t)r * 1536;
  u4v iv = *(const u4v*)(pr + c4);
  u4v ov = *(const u4v*)(pr + 512 + c4);
  u4v uv = *(const u4v*)(pr + 1024 + c4);
  f4v hv, cv; u4v hb;
#pragma unroll
  for (int x = 0; x < 4; ++x) {
    float cc = sigm(bf2f(iv[x])) * tanh_s(bf2f(uv[x]));
    float hh = sigm(bf2f(ov[x])) * tanh_s(cc);
    cv[x] = cc; hv[x] = hh; hb[x] = f2bf(hh);
  }
  *(f4v*)(h_out + (size_t)g * 512 + c4) = hv;
  *(f4v*)(c_out + (size_t)g * 512 + c4) = cv;
  *(u4v*)(HB + (size_t)g * 512 + c4) = hb;
}

// ---- merged level GEMMs: bid<nwg1 -> G1 (F); else G2 (XIOU += h@U) ------
__global__ __launch_bounds__(512, 2) void g12(
    const unsigned short* __restrict__ HB, const unsigned short* __restrict__ UFLR,
    const unsigned short* __restrict__ UCAT3, unsigned short* __restrict__ XIOU,
    unsigned short* __restrict__ F,
    int P, int shift, int start_lm1, int soff, int nwg1, int nwg2) {
  __shared__ __align__(16) unsigned short AsB[2 * 256 * 64];
  __shared__ __align__(16) unsigned short BsB[2 * 256 * 64];
  const int tid = threadIdx.x;
  const int wid = tid >> 6, lane = tid & 63;
  const int wm = wid >> 2, wn = wid & 3;
  const int lr = lane & 15, lg = lane >> 4;
  const int pmask = (1 << shift) - 1;
  f4v acc[8][4];
#pragma unroll
  for (int i = 0; i < 8; ++i)
#pragma unroll
    for (int j = 0; j < 4; ++j) acc[i][j] = fz4();

  if ((int)blockIdx.x < nwg1) {
    // ===== G1: F[2P,1024] = child_h @ UFLR^T  (K=512, NT=8) =====
    const int swz = xcd_swz(blockIdx.x, nwg1);
    const int tn = swz & 3, tm = swz >> 2;
    const int M2 = 2 * P;
    const int cmask = (2 << shift) - 1;
    const unsigned short* aA[4]; const unsigned short* aB[4];
#pragma unroll
    for (int L = 0; L < 4; ++L) {
      int q = L * 512 + tid;
      int row = q >> 3, c16g = (q & 7) ^ (row & 7);
      int jg = tm * 256 + row; if (jg >= M2) jg = M2 - 1;
      int t = jg >> (shift + 1);
      aA[L] = HB + (size_t)(t * PER_ + start_lm1 + (jg & cmask)) * 512 + c16g * 8;
      int n = tn * 256 + row;
      aB[L] = UFLR + (size_t)n * 512 + c16g * 8;
    }
#define STAGE_G1(bb, kofs)                                        \
  _Pragma("unroll") for (int L = 0; L < 4; ++L) {                 \
    int q = L * 512 + tid;                                        \
    gld16(aA[L] + (kofs), AsB + (bb) * 16384 + q * 8);            \
    gld16(aB[L] + (kofs), BsB + (bb) * 16384 + q * 8);            \
  }
    PIPE2(STAGE_G1, 8)
#pragma unroll
    for (int i = 0; i < 8; ++i)
#pragma unroll
      for (int j = 0; j < 4; ++j) {
        int n = tn * 256 + wn * 64 + j * 16 + lr;
#pragma unroll
        for (int r = 0; r < 4; ++r) {
          int jrow = tm * 256 + wm * 128 + i * 16 + lg * 4 + r;
          if (jrow < M2) F[(size_t)jrow * 1024 + n] = f2bf(acc[i][j][r]);
        }
      }
  } else {
    // ===== G2: XIOU[p] += [h_l|h_r] @ UCAT3^T  (K=1024, NT=16) =====
    const int swz = xcd_swz((int)blockIdx.x - nwg1, nwg2);
    const int tn = swz % 6, tm = swz / 6;
    const unsigned short* aA[4]; const unsigned short* aB[4];
#pragma unroll
    for (int L = 0; L < 4; ++L) {
      int q = L * 512 + tid;
      int row = q >> 3, c16g = (q & 7) ^ (row & 7);
      int p = tm * 256 + row; if (p >= P) p = P - 1;
      int t = p >> shift, kp = p & pmask;
      aA[L] = HB + (size_t)(t * PER_ + start_lm1) * 512 + (size_t)kp * 1024 + c16g * 8;
      int n = tn * 256 + row;
      aB[L] = UCAT3 + (size_t)n * 1024 + c16g * 8;
    }
#define STAGE_G2(bb, kofs)                                        \
  _Pragma("unroll") for (int L = 0; L < 4; ++L) {                 \
    int q = L * 512 + tid;                                        \
    gld16(aA[L] + (kofs), AsB + (bb) * 16384 + q * 8);            \
    gld16(aB[L] + (kofs), BsB + (bb) * 16384 + q * 8);            \
  }
    PIPE2(STAGE_G2, 16)
#pragma unroll
    for (int i = 0; i < 8; ++i)
#pragma unroll
      for (int j = 0; j < 4; ++j) {
        int n = tn * 256 + wn * 64 + j * 16 + lr;
#pragma unroll
        for (int r = 0; r < 4; ++r) {
          int p = tm * 256 + wm * 128 + i * 16 + lg * 4 + r;
          if (p < P) {
            int t = p >> shift, k = p & pmask;
            size_t mi = (size_t)(t * 1023 + soff + k);
            size_t o = mi * 1536 + n;
            XIOU[o] = f2bf(bf2f(XIOU[o]) + acc[i][j][r]);
          }
        }
      }
  }
}

// ---- g3_big: fused f-gate combine + cell update (coalesced rows) --------
__global__ __launch_bounds__(256) void g3_big(
    const unsigned short* __restrict__ F, const unsigned short* __restrict__ WF,
    const unsigned short* __restrict__ XIOU,
    float* __restrict__ h_out, float* __restrict__ c_out,
    unsigned short* __restrict__ HB,
    int P, int shift, int start_l, int start_lm1, int soff) {
  int idx = blockIdx.x * 256 + threadIdx.x;
  int p = idx >> 7;
  if (p >= P) return;
  int c4 = (idx & 127) << 2;
  int t = p >> shift, k = p & ((1 << shift) - 1);
  size_t pg = (size_t)(t * PER_ + start_l + k);
  size_t mi = (size_t)(t * 1023 + soff + k);
  size_t cg0 = (size_t)(t * PER_ + start_lm1 + 2 * k);
  const unsigned short* xr = XIOU + mi * 1536;
  u4v iv = *(const u4v*)(xr + c4);
  u4v ov = *(const u4v*)(xr + 512 + c4);
  u4v uv = *(const u4v*)(xr + 1024 + c4);
  u4v wfv = *(const u4v*)(WF + mi * 512 + c4);
  s8v f0 = *(const s8v*)(F + (size_t)(2 * p) * 1024 + 2 * c4);
  s8v f1 = *(const s8v*)(F + (size_t)(2 * p + 1) * 1024 + 2 * c4);
  f4v cc0 = *(const f4v*)(c_out + cg0 * 512 + c4);
  f4v cc1 = *(const f4v*)(c_out + (cg0 + 1) * 512 + c4);
  f4v hv, cv; u4v hb;
#pragma unroll
  for (int x = 0; x < 4; ++x) {
    float wf = bf2f(wfv[x]);
    float fc = (sigm(wf + bf2f((unsigned short)f0[2 * x])) +
                sigm(wf + bf2f((unsigned short)f0[2 * x + 1]))) * cc0[x]
             + (sigm(wf + bf2f((unsigned short)f1[2 * x])) +
                sigm(wf + bf2f((unsigned short)f1[2 * x + 1]))) * cc1[x];
    float cvv = sigm(bf2f(iv[x])) * tanh_s(bf2f(uv[x])) + fc;
    float hvv = sigm(bf2f(ov[x])) * tanh_s(cvv);
    cv[x] = cvv; hv[x] = hvv; hb[x] = f2bf(hvv);
  }
  *(f4v*)(h_out + pg * 512 + c4) = hv;
  *(f4v*)(c_out + pg * 512 + c4) = cv;
  *(u4v*)(HB + pg * 512 + c4) = hb;
}

__global__ void fill_sentinel(float* out, int n) {
  int i = blockIdx.x * 256 + threadIdx.x;
  if (i < n) out[i] = 12345.0f;
}

// ---------------- host launch -------------------------------------------
extern "C" void kernel_launch(void* const* d_in, const int* in_sizes, int n_in,
                              void* d_out, int out_size, void* d_ws, size_t ws_size,
                              hipStream_t stream) {
  (void)in_sizes; (void)n_in; (void)out_size;
  const float* feat = (const float*)d_in[0];
  const float* Wiou = (const float*)d_in[4];
  const float* biou = (const float*)d_in[5];
  const float* Ul   = (const float*)d_in[6];
  const float* Ur   = (const float*)d_in[7];
  const float* Wf   = (const float*)d_in[8];
  const float* bfb  = (const float*)d_in[9];
  const float* Ufl  = (const float*)d_in[10];
  const float* Ufr  = (const float*)d_in[11];
  float* h_out = (float*)d_out;
  float* c_out = h_out + (size_t)NN_ * 512;

  const size_t OFF_HB    = 0;
  const size_t SZ_HB     = (size_t)NN_ * 512 * 2;         // 104.8 MB
  const size_t OFF_FB    = OFF_HB + SZ_HB;
  const size_t SZ_FB     = (size_t)NN_ * 512 * 2;         // 104.8 MB
  const size_t OFF_WFm   = OFF_FB + SZ_FB;
  const size_t SZ_WF     = (size_t)NINT_ * 512 * 2;       // 52.4 MB
  const size_t OFF_WIOUB = OFF_WFm + SZ_WF;
  const size_t SZ_WIOUB  = 1536 * 512 * 2;
  const size_t OFF_UC3   = OFF_WIOUB + SZ_WIOUB;
  const size_t SZ_UC3    = 1536 * 1024 * 2;
  const size_t OFF_UFLR  = OFF_UC3 + SZ_UC3;
  const size_t SZ_UFLR   = 1024 * 512 * 2;
  const size_t OFF_WFB   = OFF_UFLR + SZ_UFLR;
  const size_t SZ_WFB    = 512 * 512 * 2;
  const size_t OFF_XIOU  = OFF_WFB + SZ_WFB;
  const size_t SZ_XIOU   = (size_t)NINT_ * 1536 * 2;      // 157.1 MB
  const size_t OFF_LF    = OFF_XIOU + SZ_XIOU;            // LIOU / F alias
  const size_t SZ_LF     = (size_t)NLEAF_ * 1536 * 2;     // 157.3 MB
  const size_t NEEDED    = OFF_LF + SZ_LF;                // ~583 MB

  if (ws_size < NEEDED) {
    int n = 2 * NN_ * 512;
    fill_sentinel<<<(n + 255) / 256, 256, 0, stream>>>((float*)d_out, n);
    return;
  }

  char* ws = (char*)d_ws;
  unsigned short* HB    = (unsigned short*)(ws + OFF_HB);
  unsigned short* FB    = (unsigned short*)(ws + OFF_FB);
  unsigned short* WF    = (unsigned short*)(ws + OFF_WFm);
  unsigned short* WIOUB = (unsigned short*)(ws + OFF_WIOUB);
  unsigned short* UCAT3 = (unsigned short*)(ws + OFF_UC3);
  unsigned short* UFLR  = (unsigned short*)(ws + OFF_UFLR);
  unsigned short* WFB   = (unsigned short*)(ws + OFF_WFB);
  unsigned short* XIOU  = (unsigned short*)(ws + OFF_XIOU);
  unsigned short* LIOU  = (unsigned short*)(ws + OFF_LF);
  unsigned short* F     = (unsigned short*)(ws + OFF_LF);

  prep_weights<<<6144, 256, 0, stream>>>(Wiou, Ul, Ur, Wf, Ufl, Ufr,
                                         WIOUB, UCAT3, UFLR, WFB);
  feat2bf<<<(NN_ * 64 + 255) / 256, 256, 0, stream>>>(feat, FB);
  {
    int nwgA = 200 * 2;    // WF   (M-tiles 200, N-tiles 2)
    int nwgB = 200 * 6;    // leaf IOU
    int nwgC = 200 * 6;    // internal XIOU
    pre_mm<<<nwgA + nwgB + nwgC, 512, 0, stream>>>(FB, WFB, WIOUB, bfb, biou,
                                                   WF, LIOU, XIOU,
                                                   nwgA, nwgB, nwgC);
  }
  leaf_ew<<<(NLEAF_ * 128) / 256, 256, 0, stream>>>(LIOU, h_out, c_out, HB);

  for (int l = 1; l <= 10; ++l) {
    int shift = 10 - l;
    int P = TREES_ << shift;
    int start_l   = 2048 - (1 << (11 - l));
    int start_lm1 = 2048 - (1 << (12 - l));
    int soff = start_l - 1024;
    int nwg1 = ((2 * P + 255) / 256) * 4;
    int nwg2 = ((P + 255) / 256) * 6;
    g12<<<nwg1 + nwg2, 512, 0, stream>>>(HB, UFLR, UCAT3, XIOU, F,
                                         P, shift, start_lm1, soff, nwg1, nwg2);
    int g3b = (P * 128 + 255) / 256;
    g3_big<<<g3b, 256, 0, stream>>>(F, WF, XIOU, h_out, c_out, HB,
                                    P, shift, start_l, start_lm1, soff);
  }
}

// Round 9
// 1698.810 us; speedup vs baseline: 1.0665x; 1.0665x over previous
//
#include <hip/hip_runtime.h>
#include <hip/hip_bf16.h>

#define TREES_ 50
#define PER_ 2047
#define NN_ (TREES_ * PER_)      // 102350 nodes
#define NINT_ (TREES_ * 1023)    // 51150 internal nodes
#define NLEAF_ (TREES_ * 1024)   // 51200 leaves

typedef __attribute__((ext_vector_type(8))) short s8v;   // 8 bf16
typedef __attribute__((ext_vector_type(4))) float f4v;   // MFMA C/D

__device__ __forceinline__ unsigned short f2bf(float f) {
  union { float f; unsigned u; } v; v.f = f;
  unsigned r = v.u + 0x7FFFu + ((v.u >> 16) & 1u);   // RNE
  return (unsigned short)(r >> 16);
}
__device__ __forceinline__ float bf2f(unsigned short s) {
  union { unsigned u; float f; } v; v.u = ((unsigned)s) << 16;
  return v.f;
}
__device__ __forceinline__ float sigm(float x) { return 1.f / (1.f + __expf(-x)); }
__device__ __forceinline__ float tanh_s(float x) {
  float ax = fabsf(x);
  float e = __expf(2.f * ax);
  float t = 1.f - 2.f / (e + 1.f);
  return copysignf(t, x);
}
__device__ __forceinline__ f4v fz4() { f4v z; z[0]=0.f; z[1]=0.f; z[2]=0.f; z[3]=0.f; return z; }

#if defined(__has_builtin)
#if __has_builtin(__builtin_amdgcn_global_load_lds)
#define HAS_GLD 1
#endif
#endif
__device__ __forceinline__ void gld16(const void* g, void* l) {
#ifdef HAS_GLD
  __builtin_amdgcn_global_load_lds(
      (const __attribute__((address_space(1))) unsigned int*)g,
      (__attribute__((address_space(3))) unsigned int*)l, 16, 0, 0);
#else
  *(s8v*)l = *(const s8v*)g;
#endif
}

// bijective XCD-chunked swizzle (m204)
__device__ __forceinline__ int xcd_swz(int bid, int nwg) {
  int q = nwg >> 3, r = nwg & 7, x = bid & 7, pos = bid >> 3;
  int base = (x < r) ? x * (q + 1) : r * (q + 1) + (x - r) * q;
  return base + pos;
}

// LDS tile [128 rows][64 bf16]; logical chunk (row,c16) at swizzled byte.
// Staging writes LINEAR slot q=(row,c16s) from global chunk c16g=c16s^(row&7).
#define LDS_BYTE(row, c16) ((row) * 128 + (((c16) ^ ((row) & 7)) << 4))

// one K-step (64) of 128x128 tile, 4 waves
#define MFMA_STEP(Ap, Bp)                                                     \
  _Pragma("unroll") for (int kk = 0; kk < 2; ++kk) {                          \
    s8v af[4], bf_[4];                                                        \
    _Pragma("unroll") for (int i = 0; i < 4; ++i) {                           \
      int R = wr * 64 + i * 16 + lr;                                          \
      af[i] = *(const s8v*)((const char*)(Ap) + LDS_BYTE(R, kk * 4 + lg));    \
    }                                                                         \
    _Pragma("unroll") for (int j = 0; j < 4; ++j) {                           \
      int R = wc * 64 + j * 16 + lr;                                          \
      bf_[j] = *(const s8v*)((const char*)(Bp) + LDS_BYTE(R, kk * 4 + lg));   \
    }                                                                         \
    _Pragma("unroll") for (int i = 0; i < 4; ++i)                             \
      _Pragma("unroll") for (int j = 0; j < 4; ++j)                           \
        acc[i][j] = __builtin_amdgcn_mfma_f32_16x16x32_bf16(af[i], bf_[j],    \
                                                            acc[i][j], 0, 0, 0); \
  }

#define VMCNT8() asm volatile("s_waitcnt vmcnt(8)" ::: "memory")
#define VMCNT0() asm volatile("s_waitcnt vmcnt(0)" ::: "memory")
#define LGKM0()  asm volatile("s_waitcnt lgkmcnt(0)" ::: "memory")
#define SBAR()   __builtin_amdgcn_s_barrier()
#define SCHEDB() __builtin_amdgcn_sched_barrier(0)

// counted-vmcnt 2-deep pipeline (R7-verified)
#define PIPELINE(STAGEM, NT)                                       \
  STAGEM(0, 0)                                                     \
  STAGEM(1, 64)                                                    \
  {                                                                \
    int cur = 0;                                                   \
    for (int t = 0; t < (NT) - 1; ++t) {                           \
      VMCNT8(); SBAR();                                            \
      __builtin_amdgcn_s_setprio(1);                               \
      MFMA_STEP(AsB + cur * 8192, BsB + cur * 8192)                \
      __builtin_amdgcn_s_setprio(0);                               \
      LGKM0(); SCHEDB(); SBAR();                                   \
      if (t + 2 < (NT)) { STAGEM(cur, (t + 2) * 64) }              \
      cur ^= 1;                                                    \
    }                                                              \
    VMCNT0(); SBAR();                                              \
    MFMA_STEP(AsB + cur * 8192, BsB + cur * 8192)                  \
  }

// ---------------- feat fp32 -> bf16 --------------------------------------
__global__ __launch_bounds__(256) void feat2bf(const float* __restrict__ feat,
                                               unsigned short* __restrict__ FB) {
  long long i = (long long)blockIdx.x * 256 + threadIdx.x;
  if (i >= (long long)NN_ * 64) return;
  const float* src = feat + i * 8;
  float4 f0 = *(const float4*)src;
  float4 f1 = *(const float4*)(src + 4);
  s8v v;
  v[0] = (short)f2bf(f0.x); v[1] = (short)f2bf(f0.y);
  v[2] = (short)f2bf(f0.z); v[3] = (short)f2bf(f0.w);
  v[4] = (short)f2bf(f1.x); v[5] = (short)f2bf(f1.y);
  v[6] = (short)f2bf(f1.z); v[7] = (short)f2bf(f1.w);
  *(s8v*)(FB + i * 8) = v;
}

// -------- weight prep --------
// UCAT2 [1536][1536]: row n = [U_iou_l[n] | U_iou_r[n] | W_iou[n]]
// UFLR  [1024][512]:  row 2c=Ufl[c], 2c+1=Ufr[c]
// WFB   [512][512]:   W_f
__global__ __launch_bounds__(256) void prep_weights(
    const float* __restrict__ Wiou, const float* __restrict__ Ul,
    const float* __restrict__ Ur,  const float* __restrict__ Wf,
    const float* __restrict__ Ufl, const float* __restrict__ Ufr,
    unsigned short* __restrict__ UCAT2, unsigned short* __restrict__ UFLR,
    unsigned short* __restrict__ WFB) {
  int i = blockIdx.x * 256 + threadIdx.x;
  if (i < 1536 * 1536) {
    int r = i / 1536, c = i - r * 1536;
    float v = (c < 512) ? Ul[r * 512 + c]
            : (c < 1024) ? Ur[r * 512 + (c - 512)]
                         : Wiou[r * 512 + (c - 1024)];
    UCAT2[i] = f2bf(v);
  }
  if (i < 1024 * 512) {
    int r = i >> 9, k = i & 511;
    int c = r >> 1, s = r & 1;
    UFLR[i] = f2bf(s ? Ufr[c * 512 + k] : Ufl[c * 512 + k]);
  }
  if (i < 512 * 512) WFB[i] = f2bf(Wf[i]);
}

// ---- WF GEMM: WF[51150,512] = FB(internal) @ W_f^T + b_f ----------------
__global__ __launch_bounds__(256) void wf_gemm(
    const unsigned short* __restrict__ FB, const unsigned short* __restrict__ WFB,
    const float* __restrict__ bfb, unsigned short* __restrict__ WF, int nwg) {
  __shared__ __align__(16) unsigned short AsB[2 * 128 * 64];
  __shared__ __align__(16) unsigned short BsB[2 * 128 * 64];
  const int tid = threadIdx.x;
  const int swz = xcd_swz(blockIdx.x, nwg);
  const int tn = swz & 3, tm = swz >> 2;
  const int wid = tid >> 6, lane = tid & 63;
  const int wr = wid >> 1, wc = wid & 1;
  const int lr = lane & 15, lg = lane >> 4;
  const unsigned short* aA[4]; const unsigned short* aB[4];
#pragma unroll
  for (int L = 0; L < 4; ++L) {
    int q = L * 256 + tid;
    int row = q >> 3, c16g = (q & 7) ^ (row & 7);
    int m = tm * 128 + row; if (m >= NINT_) m = NINT_ - 1;
    int t = (int)((unsigned)m / 1023u);
    int node = t * 2047 + 1024 + (m - t * 1023);
    aA[L] = FB + (size_t)node * 512 + c16g * 8;
    int n = tn * 128 + row;
    aB[L] = WFB + (size_t)n * 512 + c16g * 8;
  }
  f4v acc[4][4];
#pragma unroll
  for (int i = 0; i < 4; ++i)
#pragma unroll
    for (int j = 0; j < 4; ++j) acc[i][j] = fz4();
#define STAGE_W(bb, kofs)                                         \
  _Pragma("unroll") for (int L = 0; L < 4; ++L) {                 \
    int q = L * 256 + tid;                                        \
    gld16(aA[L] + (kofs), AsB + (bb) * 8192 + q * 8);             \
    gld16(aB[L] + (kofs), BsB + (bb) * 8192 + q * 8);             \
  }
  PIPELINE(STAGE_W, 8)
#pragma unroll
  for (int i = 0; i < 4; ++i)
#pragma unroll
    for (int j = 0; j < 4; ++j) {
      int n = tn * 128 + wc * 64 + j * 16 + lr;
      float bias = bfb[n];
#pragma unroll
      for (int r = 0; r < 4; ++r) {
        int m = tm * 128 + wr * 64 + i * 16 + lg * 4 + r;
        if (m < NINT_) WF[(size_t)m * 512 + n] = f2bf(acc[i][j][r] + bias);
      }
    }
}

// ---- leaf_mm: tri-gate fused leaf GEMM + activation ---------------------
// Per block: 128 leaves x 128 h-cols; gates processed i -> u -> o with the
// same A-tile; sigma/tanh combined in-register; writes h/c/HB directly
// (no LIOU intermediate, no leaf_ew pass).
__global__ __launch_bounds__(256) void leaf_mm(
    const unsigned short* __restrict__ FB, const unsigned short* __restrict__ UCAT2,
    const float* __restrict__ biou,
    float* __restrict__ h_out, float* __restrict__ c_out,
    unsigned short* __restrict__ HB, int nwg) {
  __shared__ __align__(16) unsigned short As[128 * 64];
  __shared__ __align__(16) unsigned short Bs[128 * 64];
  const int tid = threadIdx.x;
  const int swz = xcd_swz(blockIdx.x, nwg);
  const int cs = swz & 3, tm = swz >> 2;     // col-slice 0..3, M-tile 0..399
  const int wid = tid >> 6, lane = tid & 63;
  const int wr = wid >> 1, wc = wid & 1;
  const int lr = lane & 15, lg = lane >> 4;
  const unsigned short* aA[4]; const unsigned short* aB0[4];
#pragma unroll
  for (int L = 0; L < 4; ++L) {
    int q = L * 256 + tid;
    int row = q >> 3, c16g = (q & 7) ^ (row & 7);
    int m = tm * 128 + row;
    int node = (m >> 10) * 2047 + (m & 1023);          // leaf map (exact)
    aA[L] = FB + (size_t)node * 512 + c16g * 8;
    aB0[L] = UCAT2 + (size_t)(cs * 128 + row) * 1536 + 1024 + c16g * 8;  // W_iou
  }
  f4v sv[4][4];                      // sigma(i), then c
  const int goff[3] = {0, 1024, 512};   // gate row offsets: i, u, o
#pragma unroll
  for (int gg = 0; gg < 3; ++gg) {
    const size_t boff = (size_t)goff[gg] * 1536;
    f4v acc[4][4];
#pragma unroll
    for (int i = 0; i < 4; ++i)
#pragma unroll
      for (int j = 0; j < 4; ++j) acc[i][j] = fz4();
    for (int k0 = 0; k0 < 512; k0 += 64) {
#pragma unroll
      for (int L = 0; L < 4; ++L) {
        int q = L * 256 + tid;
        gld16(aA[L] + k0, (unsigned short*)As + q * 8);
        gld16(aB0[L] + boff + k0, (unsigned short*)Bs + q * 8);
      }
      __syncthreads();
      MFMA_STEP(As, Bs)
      __syncthreads();
    }
#pragma unroll
    for (int i = 0; i < 4; ++i)
#pragma unroll
      for (int j = 0; j < 4; ++j) {
        int coln = cs * 128 + wc * 64 + j * 16 + lr;
        float bias = biou[goff[gg] + coln];
#pragma unroll
        for (int r = 0; r < 4; ++r) {
          float v = acc[i][j][r] + bias;
          if (gg == 0) {
            sv[i][j][r] = sigm(v);
          } else if (gg == 1) {
            float cvv = sv[i][j][r] * tanh_s(v);
            sv[i][j][r] = cvv;
            int m = tm * 128 + wr * 64 + i * 16 + lg * 4 + r;
            int node = (m >> 10) * 2047 + (m & 1023);
            c_out[(size_t)node * 512 + coln] = cvv;
          } else {
            float hh = sigm(v) * tanh_s(sv[i][j][r]);
            int m = tm * 128 + wr * 64 + i * 16 + lg * 4 + r;
            int node = (m >> 10) * 2047 + (m & 1023);
            h_out[(size_t)node * 512 + coln] = hh;
            HB[(size_t)node * 512 + coln] = f2bf(hh);
          }
        }
      }
  }
}

// ---- merged level GEMM: bid<nwg1 -> f-gate (G1); else iou (G2) ----------
__global__ __launch_bounds__(256) void lvl_gemm(
    const unsigned short* __restrict__ HB, const unsigned short* __restrict__ FB,
    const unsigned short* __restrict__ UFLR, const unsigned short* __restrict__ UCAT2,
    const unsigned short* __restrict__ WF, const float* __restrict__ biou,
    const float* __restrict__ c_out, float* __restrict__ h_out,
    unsigned short* __restrict__ IOU,
    int P, int shift, int start_l, int start_lm1, int nwg1, int nwg2) {
  __shared__ __align__(16) unsigned short AsB[2 * 128 * 64];
  __shared__ __align__(16) unsigned short BsB[2 * 128 * 64];
  const int tid = threadIdx.x;
  const int wid = tid >> 6, lane = tid & 63;
  const int wr = wid >> 1, wc = wid & 1;
  const int lr = lane & 15, lg = lane >> 4;
  const int pmask = (1 << shift) - 1;
  f4v acc[4][4];
#pragma unroll
  for (int i = 0; i < 4; ++i)
#pragma unroll
    for (int j = 0; j < 4; ++j) acc[i][j] = fz4();

  if ((int)blockIdx.x < nwg1) {
    // ===== G1: [2P,512] @ UFLR^T ; fused fc -> h_out =====
    const int swz = xcd_swz(blockIdx.x, nwg1);
    const int tn = swz & 7, tm = swz >> 3;
    const int M2 = 2 * P;
    const int cmask = (2 << shift) - 1;
    const unsigned short* aA[4]; const unsigned short* aB[4];
#pragma unroll
    for (int L = 0; L < 4; ++L) {
      int q = L * 256 + tid;
      int row = q >> 3, c16g = (q & 7) ^ (row & 7);
      int jg = tm * 128 + row; if (jg >= M2) jg = M2 - 1;
      int t = jg >> (shift + 1), idx = jg & cmask;
      aA[L] = HB + (size_t)(t * PER_ + start_lm1 + idx) * 512 + c16g * 8;
      int n = tn * 128 + row;
      aB[L] = UFLR + (size_t)n * 512 + c16g * 8;
    }
#define STAGE_G1(bb, kofs)                                        \
  _Pragma("unroll") for (int L = 0; L < 4; ++L) {                 \
    int q = L * 256 + tid;                                        \
    gld16(aA[L] + (kofs), AsB + (bb) * 8192 + q * 8);             \
    gld16(aB[L] + (kofs), BsB + (bb) * 8192 + q * 8);             \
  }
    PIPELINE(STAGE_G1, 8)

    const int soff = start_l - 1024;           // internal-linear level offset
#pragma unroll
    for (int i = 0; i < 4; ++i) {
      int mbase = tm * 128 + wr * 64 + i * 16;  // even
#pragma unroll
      for (int j = 0; j < 4; ++j) {
        int nn = tn * 128 + wc * 64 + j * 16 + lr;
        int hcol = nn >> 1;
        float fc[4];
#pragma unroll
        for (int r = 0; r < 4; ++r) {
          int m = mbase + lg * 4 + r;           // child row
          int mm = (m < M2) ? m : 0;
          int pidx = mm >> 1;
          int t = pidx >> shift, k = pidx & pmask;
          float wf = bf2f(WF[(size_t)(t * 1023 + soff + k) * 512 + hcol]);
          float sv = sigm(wf + acc[i][j][r]);
          float spair = sv + __shfl_xor(sv, 1, 64);
          float cc = 0.f;
          if ((lr & 1) == 0)
            cc = c_out[(size_t)(t * PER_ + start_lm1 + (mm & cmask)) * 512 + hcol];
          fc[r] = spair * cc;
        }
        if ((lr & 1) == 0) {
          int p0 = (mbase >> 1) + lg * 2;
          if (p0 < P) {
            int t0 = p0 >> shift, k0p = p0 & pmask;
            h_out[(size_t)(t0 * PER_ + start_l + k0p) * 512 + hcol] = fc[0] + fc[1];
          }
          int p1 = (mbase >> 1) + lg * 2 + 1;
          if (p1 < P) {
            int t1 = p1 >> shift, k1p = p1 & pmask;
            h_out[(size_t)(t1 * PER_ + start_l + k1p) * 512 + hcol] = fc[2] + fc[3];
          }
        }
      }
    }
  } else {
    // ===== G2: [P, 1536=(hl|hr|x_p)] @ UCAT2^T + b -> IOU =====
    const int swz = xcd_swz((int)blockIdx.x - nwg1, nwg2);
    const int tn = swz % 12, tm = swz / 12;
    const unsigned short* aHB[4]; const unsigned short* aFB[4];
    const unsigned short* aB[4];
#pragma unroll
    for (int L = 0; L < 4; ++L) {
      int q = L * 256 + tid;
      int row = q >> 3, c16g = (q & 7) ^ (row & 7);
      int p = tm * 128 + row; if (p >= P) p = P - 1;
      int t = p >> shift, kp = p & pmask;
      aHB[L] = HB + (size_t)(t * PER_ + start_lm1) * 512 + (size_t)kp * 1024 + c16g * 8;
      aFB[L] = FB + (size_t)(t * PER_ + start_l + kp) * 512 + c16g * 8 - 1024;
      int n = tn * 128 + row;
      aB[L] = UCAT2 + (size_t)n * 1536 + c16g * 8;
    }
#define STAGE_G2(bb, kofs)                                                    \
  _Pragma("unroll") for (int L = 0; L < 4; ++L) {                             \
    int q = L * 256 + tid;                                                    \
    const unsigned short* srcA =                                              \
        ((kofs) < 1024) ? aHB[L] + (kofs) : aFB[L] + (kofs);                  \
    gld16(srcA, AsB + (bb) * 8192 + q * 8);                                   \
    gld16(aB[L] + (kofs), BsB + (bb) * 8192 + q * 8);                         \
  }
    PIPELINE(STAGE_G2, 24)
#pragma unroll
    for (int i = 0; i < 4; ++i)
#pragma unroll
      for (int j = 0; j < 4; ++j) {
        int n = tn * 128 + wc * 64 + j * 16 + lr;
        float bias = biou[n];
#pragma unroll
        for (int r = 0; r < 4; ++r) {
          int m = tm * 128 + wr * 64 + i * 16 + lg * 4 + r;
          if (m < P) IOU[(size_t)m * 1536 + n] = f2bf(acc[i][j][r] + bias);
        }
      }
  }
}

// ---- G3: combine; reads fcsum from h_out, overwrites with h -------------
__global__ __launch_bounds__(256) void g3_kernel(
    const unsigned short* __restrict__ IOU,
    float* __restrict__ h_out, float* __restrict__ c_out,
    unsigned short* __restrict__ HB, int P, int shift, int start_l) {
  int idx = blockIdx.x * 256 + threadIdx.x;
  int p = idx >> 7;
  if (p >= P) return;
  int c4 = (idx & 127) << 2;
  int t = p >> shift, k = p & ((1 << shift) - 1);
  size_t pg = (size_t)(t * PER_ + start_l + k);
  const unsigned short* ir = IOU + (size_t)p * 1536;
  ushort4 iv = *(const ushort4*)(ir + c4);
  ushort4 ov = *(const ushort4*)(ir + 512 + c4);
  ushort4 uv = *(const ushort4*)(ir + 1024 + c4);
  float4 fcs = *(const float4*)(h_out + pg * 512 + c4);
  float4 hv, cv; ushort4 hb;
  float cc, hh;
  cc = sigm(bf2f(iv.x)) * tanh_s(bf2f(uv.x)) + fcs.x; hh = sigm(bf2f(ov.x)) * tanh_s(cc);
  cv.x = cc; hv.x = hh; hb.x = f2bf(hh);
  cc = sigm(bf2f(iv.y)) * tanh_s(bf2f(uv.y)) + fcs.y; hh = sigm(bf2f(ov.y)) * tanh_s(cc);
  cv.y = cc; hv.y = hh; hb.y = f2bf(hh);
  cc = sigm(bf2f(iv.z)) * tanh_s(bf2f(uv.z)) + fcs.z; hh = sigm(bf2f(ov.z)) * tanh_s(cc);
  cv.z = cc; hv.z = hh; hb.z = f2bf(hh);
  cc = sigm(bf2f(iv.w)) * tanh_s(bf2f(uv.w)) + fcs.w; hh = sigm(bf2f(ov.w)) * tanh_s(cc);
  cv.w = cc; hv.w = hh; hb.w = f2bf(hh);
  *(float4*)(h_out + pg * 512 + c4) = hv;
  *(float4*)(c_out + pg * 512 + c4) = cv;
  *(ushort4*)(HB + pg * 512 + c4) = hb;
}

__global__ void fill_sentinel(float* out, int n) {
  int i = blockIdx.x * 256 + threadIdx.x;
  if (i < n) out[i] = 12345.0f;
}

// ---------------- host launch -------------------------------------------
extern "C" void kernel_launch(void* const* d_in, const int* in_sizes, int n_in,
                              void* d_out, int out_size, void* d_ws, size_t ws_size,
                              hipStream_t stream) {
  (void)in_sizes; (void)n_in; (void)out_size;
  const float* feat = (const float*)d_in[0];
  const float* Wiou = (const float*)d_in[4];
  const float* biou = (const float*)d_in[5];
  const float* Ul   = (const float*)d_in[6];
  const float* Ur   = (const float*)d_in[7];
  const float* Wf   = (const float*)d_in[8];
  const float* bfb  = (const float*)d_in[9];
  const float* Ufl  = (const float*)d_in[10];
  const float* Ufr  = (const float*)d_in[11];
  float* h_out = (float*)d_out;
  float* c_out = h_out + (size_t)NN_ * 512;

  const size_t OFF_HB   = 0;
  const size_t SZ_HB    = (size_t)NN_ * 512 * 2;          // 104.8 MB
  const size_t OFF_FB   = OFF_HB + SZ_HB;
  const size_t SZ_FB    = (size_t)NN_ * 512 * 2;          // 104.8 MB
  const size_t OFF_WFm  = OFF_FB + SZ_FB;
  const size_t SZ_WF    = (size_t)NINT_ * 512 * 2;        // 52.4 MB
  const size_t OFF_UC2  = OFF_WFm + SZ_WF;
  const size_t SZ_UC2   = 1536 * 1536 * 2;
  const size_t OFF_UFLR = OFF_UC2 + SZ_UC2;
  const size_t SZ_UFLR  = 1024 * 512 * 2;
  const size_t OFF_WFB  = OFF_UFLR + SZ_UFLR;
  const size_t SZ_WFB   = 512 * 512 * 2;
  const size_t OFF_IOU  = OFF_WFB + SZ_WFB;
  const size_t SZ_IOU   = (size_t)25600 * 1536 * 2;       // 78.6 MB (level-1 P)
  const size_t NEEDED   = OFF_IOU + SZ_IOU;               // ~347 MB

  if (ws_size < NEEDED) {
    int n = 2 * NN_ * 512;
    fill_sentinel<<<(n + 255) / 256, 256, 0, stream>>>((float*)d_out, n);
    return;
  }

  char* ws = (char*)d_ws;
  unsigned short* HB    = (unsigned short*)(ws + OFF_HB);
  unsigned short* FB    = (unsigned short*)(ws + OFF_FB);
  unsigned short* WF    = (unsigned short*)(ws + OFF_WFm);
  unsigned short* UCAT2 = (unsigned short*)(ws + OFF_UC2);
  unsigned short* UFLR  = (unsigned short*)(ws + OFF_UFLR);
  unsigned short* WFB   = (unsigned short*)(ws + OFF_WFB);
  unsigned short* IOU   = (unsigned short*)(ws + OFF_IOU);

  prep_weights<<<9216, 256, 0, stream>>>(Wiou, Ul, Ur, Wf, Ufl, Ufr,
                                         UCAT2, UFLR, WFB);
  feat2bf<<<(NN_ * 64 + 255) / 256, 256, 0, stream>>>(feat, FB);
  {
    int nwgW = ((NINT_ + 127) / 128) * 4;      // 1600
    wf_gemm<<<nwgW, 256, 0, stream>>>(FB, WFB, bfb, WF, nwgW);
  }
  {
    int nwgL = (NLEAF_ / 128) * 4;             // 1600 (400 M-tiles x 4 col-slices)
    leaf_mm<<<nwgL, 256, 0, stream>>>(FB, UCAT2, biou, h_out, c_out, HB, nwgL);
  }

  for (int l = 1; l <= 10; ++l) {
    int shift = 10 - l;
    int P = TREES_ << shift;
    int start_l   = 2048 - (1 << (11 - l));
    int start_lm1 = 2048 - (1 << (12 - l));
    int nwg1 = ((2 * P + 127) / 128) * 8;
    int nwg2 = ((P + 127) / 128) * 12;
    lvl_gemm<<<nwg1 + nwg2, 256, 0, stream>>>(HB, FB, UFLR, UCAT2, WF, biou,
                                              c_out, h_out, IOU,
                                              P, shift, start_l, start_lm1,
                                              nwg1, nwg2);
    int g3b = (P * 128 + 255) / 256;
    g3_kernel<<<g3b, 256, 0, stream>>>(IOU, h_out, c_out, HB, P, shift, start_l);
  }
}

// Round 10
// 1460.778 us; speedup vs baseline: 1.2403x; 1.1629x over previous
//
#include <hip/hip_runtime.h>
#include <hip/hip_bf16.h>

#define TREES_ 50
#define PER_ 2047
#define NN_ (TREES_ * PER_)      // 102350 nodes
#define NINT_ (TREES_ * 1023)    // 51150 internal nodes
#define NLEAF_ (TREES_ * 1024)   // 51200 leaves

typedef __attribute__((ext_vector_type(8))) short s8v;   // 8 bf16
typedef __attribute__((ext_vector_type(4))) float f4v;   // MFMA C/D

__device__ __forceinline__ unsigned short f2bf(float f) {
  union { float f; unsigned u; } v; v.f = f;
  unsigned r = v.u + 0x7FFFu + ((v.u >> 16) & 1u);   // RNE
  return (unsigned short)(r >> 16);
}
__device__ __forceinline__ float bf2f(unsigned short s) {
  union { unsigned u; float f; } v; v.u = ((unsigned)s) << 16;
  return v.f;
}
__device__ __forceinline__ float sigm(float x) { return 1.f / (1.f + __expf(-x)); }
__device__ __forceinline__ float tanh_s(float x) {
  float ax = fabsf(x);
  float e = __expf(2.f * ax);
  float t = 1.f - 2.f / (e + 1.f);
  return copysignf(t, x);
}
__device__ __forceinline__ f4v fz4() { f4v z; z[0]=0.f; z[1]=0.f; z[2]=0.f; z[3]=0.f; return z; }

#if defined(__has_builtin)
#if __has_builtin(__builtin_amdgcn_global_load_lds)
#define HAS_GLD 1
#endif
#endif
__device__ __forceinline__ void gld16(const void* g, void* l) {
#ifdef HAS_GLD
  __builtin_amdgcn_global_load_lds(
      (const __attribute__((address_space(1))) unsigned int*)g,
      (__attribute__((address_space(3))) unsigned int*)l, 16, 0, 0);
#else
  *(s8v*)l = *(const s8v*)g;
#endif
}

// bijective XCD-chunked swizzle (m204)
__device__ __forceinline__ int xcd_swz(int bid, int nwg) {
  int q = nwg >> 3, r = nwg & 7, x = bid & 7, pos = bid >> 3;
  int base = (x < r) ? x * (q + 1) : r * (q + 1) + (x - r) * q;
  return base + pos;
}

// LDS tile [128 rows][64 bf16]; logical chunk (row,c16) at swizzled byte.
// Staging writes LINEAR slot q=(row,c16s) from global chunk c16g=c16s^(row&7).
#define LDS_BYTE(row, c16) ((row) * 128 + (((c16) ^ ((row) & 7)) << 4))

// one K-step (64) of 128x128 tile, 4 waves
#define MFMA_STEP(Ap, Bp)                                                     \
  _Pragma("unroll") for (int kk = 0; kk < 2; ++kk) {                          \
    s8v af[4], bf_[4];                                                        \
    _Pragma("unroll") for (int i = 0; i < 4; ++i) {                           \
      int R = wr * 64 + i * 16 + lr;                                          \
      af[i] = *(const s8v*)((const char*)(Ap) + LDS_BYTE(R, kk * 4 + lg));    \
    }                                                                         \
    _Pragma("unroll") for (int j = 0; j < 4; ++j) {                           \
      int R = wc * 64 + j * 16 + lr;                                          \
      bf_[j] = *(const s8v*)((const char*)(Bp) + LDS_BYTE(R, kk * 4 + lg));   \
    }                                                                         \
    _Pragma("unroll") for (int i = 0; i < 4; ++i)                             \
      _Pragma("unroll") for (int j = 0; j < 4; ++j)                           \
        acc[i][j] = __builtin_amdgcn_mfma_f32_16x16x32_bf16(af[i], bf_[j],    \
                                                            acc[i][j], 0, 0, 0); \
  }

#define VMCNT8() asm volatile("s_waitcnt vmcnt(8)" ::: "memory")
#define VMCNT4() asm volatile("s_waitcnt vmcnt(4)" ::: "memory")
#define VMCNT0() asm volatile("s_waitcnt vmcnt(0)" ::: "memory")
#define LGKM0()  asm volatile("s_waitcnt lgkmcnt(0)" ::: "memory")
#define SBAR()   __builtin_amdgcn_s_barrier()
#define SCHEDB() __builtin_amdgcn_sched_barrier(0)

// R7-verified counted-vmcnt 2-deep pipeline (all-gld staging) — used by pre_mm
#define PIPELINE(STAGEM, NT)                                       \
  STAGEM(0, 0)                                                     \
  STAGEM(1, 64)                                                    \
  {                                                                \
    int cur = 0;                                                   \
    for (int t = 0; t < (NT) - 1; ++t) {                           \
      VMCNT8(); SBAR();                                            \
      __builtin_amdgcn_s_setprio(1);                               \
      MFMA_STEP(AsB + cur * 8192, BsB + cur * 8192)                \
      __builtin_amdgcn_s_setprio(0);                               \
      LGKM0(); SCHEDB(); SBAR();                                   \
      if (t + 2 < (NT)) { STAGEM(cur, (t + 2) * 64) }              \
      cur ^= 1;                                                    \
    }                                                              \
    VMCNT0(); SBAR();                                              \
    MFMA_STEP(AsB + cur * 8192, BsB + cur * 8192)                  \
  }

// HYBRID pipeline: A via global_load_lds, B via reg-load + ds_write_b128.
// bregs hold tile t+1's B while tile t computes. vmcnt bookkeeping:
//   steady outstanding after stage-point = {bload,gldA}_{t+2} = 8
//   iter-top VMCNT8 -> gldA_{t+1} drained; VMCNT4 at stage-point -> bload_{t+1}
//   in regs before its ds_write; LGKM0 before each SBAR makes ds_writes visible.
#define BDSW(bb)                                                   \
  _Pragma("unroll") for (int L = 0; L < 4; ++L) {                  \
    int q = L * 256 + tid;                                         \
    *(s8v*)(BsB + (bb) * 8192 + q * 8) = breg[L];                  \
  }
#define PIPELINE_H(AL, BL, NT)                                     \
  BL(0) AL(0, 0)                                                   \
  VMCNT4(); BDSW(0)                                                \
  BL(64) AL(1, 64)                                                 \
  {                                                                \
    int cur = 0;                                                   \
    for (int t = 0; t < (NT) - 1; ++t) {                           \
      VMCNT8(); LGKM0(); SBAR();                                   \
      __builtin_amdgcn_s_setprio(1);                               \
      MFMA_STEP(AsB + cur * 8192, BsB + cur * 8192)                \
      __builtin_amdgcn_s_setprio(0);                               \
      LGKM0(); SCHEDB(); SBAR();                                   \
      VMCNT4(); BDSW(cur ^ 1)                                      \
      if (t + 2 < (NT)) { BL((t + 2) * 64) AL(cur, (t + 2) * 64) } \
      cur ^= 1;                                                    \
    }                                                              \
    VMCNT0(); LGKM0(); SBAR();                                     \
    MFMA_STEP(AsB + cur * 8192, BsB + cur * 8192)                  \
  }

// ---------------- feat fp32 -> bf16 --------------------------------------
__global__ __launch_bounds__(256) void feat2bf(const float* __restrict__ feat,
                                               unsigned short* __restrict__ FB) {
  long long i = (long long)blockIdx.x * 256 + threadIdx.x;
  if (i >= (long long)NN_ * 64) return;
  const float* src = feat + i * 8;
  float4 f0 = *(const float4*)src;
  float4 f1 = *(const float4*)(src + 4);
  s8v v;
  v[0] = (short)f2bf(f0.x); v[1] = (short)f2bf(f0.y);
  v[2] = (short)f2bf(f0.z); v[3] = (short)f2bf(f0.w);
  v[4] = (short)f2bf(f1.x); v[5] = (short)f2bf(f1.y);
  v[6] = (short)f2bf(f1.z); v[7] = (short)f2bf(f1.w);
  *(s8v*)(FB + i * 8) = v;
}

// -------- weight prep --------
// UCAT2 [1536][1536]: row n = [U_iou_l[n] | U_iou_r[n] | W_iou[n]]
// UFLR  [1024][512]:  row 2c=Ufl[c], 2c+1=Ufr[c]
// WFB   [512][512]:   W_f
__global__ __launch_bounds__(256) void prep_weights(
    const float* __restrict__ Wiou, const float* __restrict__ Ul,
    const float* __restrict__ Ur,  const float* __restrict__ Wf,
    const float* __restrict__ Ufl, const float* __restrict__ Ufr,
    unsigned short* __restrict__ UCAT2, unsigned short* __restrict__ UFLR,
    unsigned short* __restrict__ WFB) {
  int i = blockIdx.x * 256 + threadIdx.x;
  if (i < 1536 * 1536) {
    int r = i / 1536, c = i - r * 1536;
    float v = (c < 512) ? Ul[r * 512 + c]
            : (c < 1024) ? Ur[r * 512 + (c - 512)]
                         : Wiou[r * 512 + (c - 1024)];
    UCAT2[i] = f2bf(v);
  }
  if (i < 1024 * 512) {
    int r = i >> 9, k = i & 511;
    int c = r >> 1, s = r & 1;
    UFLR[i] = f2bf(s ? Ufr[c * 512 + k] : Ufl[c * 512 + k]);
  }
  if (i < 512 * 512) WFB[i] = f2bf(Wf[i]);
}

// ---- merged pre GEMMs (CONTROL: all-gld staging): WF | leaf LIOU --------
__global__ __launch_bounds__(256) void pre_mm(
    const unsigned short* __restrict__ FB, const unsigned short* __restrict__ WFB,
    const unsigned short* __restrict__ UCAT2,
    const float* __restrict__ bfb, const float* __restrict__ biou,
    unsigned short* __restrict__ WF, unsigned short* __restrict__ LIOU,
    int nwgW, int nwgL) {
  __shared__ __align__(16) unsigned short AsB[2 * 128 * 64];
  __shared__ __align__(16) unsigned short BsB[2 * 128 * 64];
  const int tid = threadIdx.x;
  const int wid = tid >> 6, lane = tid & 63;
  const int wr = wid >> 1, wc = wid & 1;
  const int lr = lane & 15, lg = lane >> 4;
  f4v acc[4][4];
#pragma unroll
  for (int i = 0; i < 4; ++i)
#pragma unroll
    for (int j = 0; j < 4; ++j) acc[i][j] = fz4();

  const unsigned short* aA[4]; const unsigned short* aB[4];
  int tm, tn;
  const bool isW = (int)blockIdx.x < nwgW;
  if (isW) {
    const int swz = xcd_swz(blockIdx.x, nwgW);
    tn = swz & 3; tm = swz >> 2;
#pragma unroll
    for (int L = 0; L < 4; ++L) {
      int q = L * 256 + tid;
      int row = q >> 3, c16g = (q & 7) ^ (row & 7);
      int m = tm * 128 + row; if (m >= NINT_) m = NINT_ - 1;
      int t = (int)((unsigned)m / 1023u);
      int node = t * 2047 + 1024 + (m - t * 1023);
      aA[L] = FB + (size_t)node * 512 + c16g * 8;
      int n = tn * 128 + row;
      aB[L] = WFB + (size_t)n * 512 + c16g * 8;
    }
  } else {
    const int swz = xcd_swz((int)blockIdx.x - nwgW, nwgL);
    tn = swz % 12; tm = swz / 12;
#pragma unroll
    for (int L = 0; L < 4; ++L) {
      int q = L * 256 + tid;
      int row = q >> 3, c16g = (q & 7) ^ (row & 7);
      int m = tm * 128 + row;
      int node = (m >> 10) * 2047 + (m & 1023);
      aA[L] = FB + (size_t)node * 512 + c16g * 8;
      int n = tn * 128 + row;
      aB[L] = UCAT2 + (size_t)n * 1536 + 1024 + c16g * 8;  // W_iou slice
    }
  }
#define STAGE_P(bb, kofs)                                         \
  _Pragma("unroll") for (int L = 0; L < 4; ++L) {                 \
    int q = L * 256 + tid;                                        \
    gld16(aA[L] + (kofs), AsB + (bb) * 8192 + q * 8);             \
    gld16(aB[L] + (kofs), BsB + (bb) * 8192 + q * 8);             \
  }
  PIPELINE(STAGE_P, 8)

  if (isW) {
#pragma unroll
    for (int i = 0; i < 4; ++i)
#pragma unroll
      for (int j = 0; j < 4; ++j) {
        int n = tn * 128 + wc * 64 + j * 16 + lr;
        float bias = bfb[n];
#pragma unroll
        for (int r = 0; r < 4; ++r) {
          int m = tm * 128 + wr * 64 + i * 16 + lg * 4 + r;
          if (m < NINT_) WF[(size_t)m * 512 + n] = f2bf(acc[i][j][r] + bias);
        }
      }
  } else {
#pragma unroll
    for (int i = 0; i < 4; ++i)
#pragma unroll
      for (int j = 0; j < 4; ++j) {
        int n = tn * 128 + wc * 64 + j * 16 + lr;
        float bias = biou[n];
#pragma unroll
        for (int r = 0; r < 4; ++r) {
          int m = tm * 128 + wr * 64 + i * 16 + lg * 4 + r;
          LIOU[(size_t)m * 1536 + n] = f2bf(acc[i][j][r] + bias);
        }
      }
  }
}

// ---- leaf elementwise ---------------------------------------------------
__global__ __launch_bounds__(256) void leaf_ew(
    const unsigned short* __restrict__ LIOU,
    float* __restrict__ h_out, float* __restrict__ c_out,
    unsigned short* __restrict__ HB) {
  int idx = blockIdx.x * 256 + threadIdx.x;
  int r = idx >> 7;
  int c4 = (idx & 127) << 2;
  int g = (r >> 10) * 2047 + (r & 1023);
  const unsigned short* pr = LIOU + (size_t)r * 1536;
  ushort4 iv = *(const ushort4*)(pr + c4);
  ushort4 ov = *(const ushort4*)(pr + 512 + c4);
  ushort4 uv = *(const ushort4*)(pr + 1024 + c4);
  float4 hv, cv; ushort4 hb;
  float cc, hh;
  cc = sigm(bf2f(iv.x)) * tanh_s(bf2f(uv.x)); hh = sigm(bf2f(ov.x)) * tanh_s(cc);
  cv.x = cc; hv.x = hh; hb.x = f2bf(hh);
  cc = sigm(bf2f(iv.y)) * tanh_s(bf2f(uv.y)); hh = sigm(bf2f(ov.y)) * tanh_s(cc);
  cv.y = cc; hv.y = hh; hb.y = f2bf(hh);
  cc = sigm(bf2f(iv.z)) * tanh_s(bf2f(uv.z)); hh = sigm(bf2f(ov.z)) * tanh_s(cc);
  cv.z = cc; hv.z = hh; hb.z = f2bf(hh);
  cc = sigm(bf2f(iv.w)) * tanh_s(bf2f(uv.w)); hh = sigm(bf2f(ov.w)) * tanh_s(cc);
  cv.w = cc; hv.w = hh; hb.w = f2bf(hh);
  *(float4*)(h_out + (size_t)g * 512 + c4) = hv;
  *(float4*)(c_out + (size_t)g * 512 + c4) = cv;
  *(ushort4*)(HB + (size_t)g * 512 + c4) = hb;
}

// ---- merged level GEMM (EXPERIMENT: hybrid staging) ---------------------
__global__ __launch_bounds__(256) void lvl_gemm(
    const unsigned short* __restrict__ HB, const unsigned short* __restrict__ FB,
    const unsigned short* __restrict__ UFLR, const unsigned short* __restrict__ UCAT2,
    const unsigned short* __restrict__ WF, const float* __restrict__ biou,
    const float* __restrict__ c_out, float* __restrict__ h_out,
    unsigned short* __restrict__ IOU,
    int P, int shift, int start_l, int start_lm1, int nwg1, int nwg2) {
  __shared__ __align__(16) unsigned short AsB[2 * 128 * 64];
  __shared__ __align__(16) unsigned short BsB[2 * 128 * 64];
  const int tid = threadIdx.x;
  const int wid = tid >> 6, lane = tid & 63;
  const int wr = wid >> 1, wc = wid & 1;
  const int lr = lane & 15, lg = lane >> 4;
  const int pmask = (1 << shift) - 1;
  f4v acc[4][4];
#pragma unroll
  for (int i = 0; i < 4; ++i)
#pragma unroll
    for (int j = 0; j < 4; ++j) acc[i][j] = fz4();

  if ((int)blockIdx.x < nwg1) {
    // ===== G1: [2P,512] @ UFLR^T ; fused fc -> h_out =====
    const int swz = xcd_swz(blockIdx.x, nwg1);
    const int tn = swz & 7, tm = swz >> 3;
    const int M2 = 2 * P;
    const int cmask = (2 << shift) - 1;
    const unsigned short* aA[4]; const unsigned short* aB[4];
#pragma unroll
    for (int L = 0; L < 4; ++L) {
      int q = L * 256 + tid;
      int row = q >> 3, c16g = (q & 7) ^ (row & 7);
      int jg = tm * 128 + row; if (jg >= M2) jg = M2 - 1;
      int t = jg >> (shift + 1), idx = jg & cmask;
      aA[L] = HB + (size_t)(t * PER_ + start_lm1 + idx) * 512 + c16g * 8;
      int n = tn * 128 + row;
      aB[L] = UFLR + (size_t)n * 512 + c16g * 8;
    }
    s8v breg[4];
#define AL_G1(bb, kofs)                                           \
  _Pragma("unroll") for (int L = 0; L < 4; ++L) {                 \
    int q = L * 256 + tid;                                        \
    gld16(aA[L] + (kofs), AsB + (bb) * 8192 + q * 8);             \
  }
#define BL_G1(kofs)                                               \
  _Pragma("unroll") for (int L = 0; L < 4; ++L)                   \
    breg[L] = *(const s8v*)(aB[L] + (kofs));
    PIPELINE_H(AL_G1, BL_G1, 8)

    const int soff = start_l - 1024;           // internal-linear level offset
#pragma unroll
    for (int i = 0; i < 4; ++i) {
      int mbase = tm * 128 + wr * 64 + i * 16;  // even
#pragma unroll
      for (int j = 0; j < 4; ++j) {
        int nn = tn * 128 + wc * 64 + j * 16 + lr;
        int hcol = nn >> 1;
        float fc[4];
#pragma unroll
        for (int r = 0; r < 4; ++r) {
          int m = mbase + lg * 4 + r;           // child row
          int mm = (m < M2) ? m : 0;
          int pidx = mm >> 1;
          int t = pidx >> shift, k = pidx & pmask;
          float wf = bf2f(WF[(size_t)(t * 1023 + soff + k) * 512 + hcol]);
          float sv = sigm(wf + acc[i][j][r]);
          float spair = sv + __shfl_xor(sv, 1, 64);
          float cc = 0.f;
          if ((lr & 1) == 0)
            cc = c_out[(size_t)(t * PER_ + start_lm1 + (mm & cmask)) * 512 + hcol];
          fc[r] = spair * cc;
        }
        if ((lr & 1) == 0) {
          int p0 = (mbase >> 1) + lg * 2;
          if (p0 < P) {
            int t0 = p0 >> shift, k0p = p0 & pmask;
            h_out[(size_t)(t0 * PER_ + start_l + k0p) * 512 + hcol] = fc[0] + fc[1];
          }
          int p1 = (mbase >> 1) + lg * 2 + 1;
          if (p1 < P) {
            int t1 = p1 >> shift, k1p = p1 & pmask;
            h_out[(size_t)(t1 * PER_ + start_l + k1p) * 512 + hcol] = fc[2] + fc[3];
          }
        }
      }
    }
  } else {
    // ===== G2: [P, 1536=(hl|hr|x_p)] @ UCAT2^T + b -> IOU =====
    const int swz = xcd_swz((int)blockIdx.x - nwg1, nwg2);
    const int tn = swz % 12, tm = swz / 12;
    const unsigned short* aHB[4]; const unsigned short* aFB[4];
    const unsigned short* aB[4];
#pragma unroll
    for (int L = 0; L < 4; ++L) {
      int q = L * 256 + tid;
      int row = q >> 3, c16g = (q & 7) ^ (row & 7);
      int p = tm * 128 + row; if (p >= P) p = P - 1;
      int t = p >> shift, kp = p & pmask;
      aHB[L] = HB + (size_t)(t * PER_ + start_lm1) * 512 + (size_t)kp * 1024 + c16g * 8;
      aFB[L] = FB + (size_t)(t * PER_ + start_l + kp) * 512 + c16g * 8 - 1024;
      int n = tn * 128 + row;
      aB[L] = UCAT2 + (size_t)n * 1536 + c16g * 8;
    }
    s8v breg[4];
#define AL_G2(bb, kofs)                                                       \
  _Pragma("unroll") for (int L = 0; L < 4; ++L) {                             \
    int q = L * 256 + tid;                                                    \
    const unsigned short* srcA =                                              \
        ((kofs) < 1024) ? aHB[L] + (kofs) : aFB[L] + (kofs);                  \
    gld16(srcA, AsB + (bb) * 8192 + q * 8);                                   \
  }
#define BL_G2(kofs)                                                           \
  _Pragma("unroll") for (int L = 0; L < 4; ++L)                               \
    breg[L] = *(const s8v*)(aB[L] + (kofs));
    PIPELINE_H(AL_G2, BL_G2, 24)
#pragma unroll
    for (int i = 0; i < 4; ++i)
#pragma unroll
      for (int j = 0; j < 4; ++j) {
        int n = tn * 128 + wc * 64 + j * 16 + lr;
        float bias = biou[n];
#pragma unroll
        for (int r = 0; r < 4; ++r) {
          int m = tm * 128 + wr * 64 + i * 16 + lg * 4 + r;
          if (m < P) IOU[(size_t)m * 1536 + n] = f2bf(acc[i][j][r] + bias);
        }
      }
  }
}

// ---- G3: combine; reads fcsum from h_out, overwrites with h -------------
__global__ __launch_bounds__(256) void g3_kernel(
    const unsigned short* __restrict__ IOU,
    float* __restrict__ h_out, float* __restrict__ c_out,
    unsigned short* __restrict__ HB, int P, int shift, int start_l) {
  int idx = blockIdx.x * 256 + threadIdx.x;
  int p = idx >> 7;
  if (p >= P) return;
  int c4 = (idx & 127) << 2;
  int t = p >> shift, k = p & ((1 << shift) - 1);
  size_t pg = (size_t)(t * PER_ + start_l + k);
  const unsigned short* ir = IOU + (size_t)p * 1536;
  ushort4 iv = *(const ushort4*)(ir + c4);
  ushort4 ov = *(const ushort4*)(ir + 512 + c4);
  ushort4 uv = *(const ushort4*)(ir + 1024 + c4);
  float4 fcs = *(const float4*)(h_out + pg * 512 + c4);
  float4 hv, cv; ushort4 hb;
  float cc, hh;
  cc = sigm(bf2f(iv.x)) * tanh_s(bf2f(uv.x)) + fcs.x; hh = sigm(bf2f(ov.x)) * tanh_s(cc);
  cv.x = cc; hv.x = hh; hb.x = f2bf(hh);
  cc = sigm(bf2f(iv.y)) * tanh_s(bf2f(uv.y)) + fcs.y; hh = sigm(bf2f(ov.y)) * tanh_s(cc);
  cv.y = cc; hv.y = hh; hb.y = f2bf(hh);
  cc = sigm(bf2f(iv.z)) * tanh_s(bf2f(uv.z)) + fcs.z; hh = sigm(bf2f(ov.z)) * tanh_s(cc);
  cv.z = cc; hv.z = hh; hb.z = f2bf(hh);
  cc = sigm(bf2f(iv.w)) * tanh_s(bf2f(uv.w)) + fcs.w; hh = sigm(bf2f(ov.w)) * tanh_s(cc);
  cv.w = cc; hv.w = hh; hb.w = f2bf(hh);
  *(float4*)(h_out + pg * 512 + c4) = hv;
  *(float4*)(c_out + pg * 512 + c4) = cv;
  *(ushort4*)(HB + pg * 512 + c4) = hb;
}

__global__ void fill_sentinel(float* out, int n) {
  int i = blockIdx.x * 256 + threadIdx.x;
  if (i < n) out[i] = 12345.0f;
}

// ---------------- host launch -------------------------------------------
extern "C" void kernel_launch(void* const* d_in, const int* in_sizes, int n_in,
                              void* d_out, int out_size, void* d_ws, size_t ws_size,
                              hipStream_t stream) {
  (void)in_sizes; (void)n_in; (void)out_size;
  const float* feat = (const float*)d_in[0];
  const float* Wiou = (const float*)d_in[4];
  const float* biou = (const float*)d_in[5];
  const float* Ul   = (const float*)d_in[6];
  const float* Ur   = (const float*)d_in[7];
  const float* Wf   = (const float*)d_in[8];
  const float* bfb  = (const float*)d_in[9];
  const float* Ufl  = (const float*)d_in[10];
  const float* Ufr  = (const float*)d_in[11];
  float* h_out = (float*)d_out;
  float* c_out = h_out + (size_t)NN_ * 512;

  const size_t OFF_HB   = 0;
  const size_t SZ_HB    = (size_t)NN_ * 512 * 2;
  const size_t OFF_FB   = OFF_HB + SZ_HB;
  const size_t SZ_FB    = (size_t)NN_ * 512 * 2;
  const size_t OFF_WFm  = OFF_FB + SZ_FB;
  const size_t SZ_WF    = (size_t)NINT_ * 512 * 2;
  const size_t OFF_UC2  = OFF_WFm + SZ_WF;
  const size_t SZ_UC2   = 1536 * 1536 * 2;
  const size_t OFF_UFLR = OFF_UC2 + SZ_UC2;
  const size_t SZ_UFLR  = 1024 * 512 * 2;
  const size_t OFF_WFB  = OFF_UFLR + SZ_UFLR;
  const size_t SZ_WFB   = 512 * 512 * 2;
  const size_t OFF_LIOU = OFF_WFB + SZ_WFB;               // LIOU / IOU alias
  const size_t SZ_LIOU  = (size_t)NLEAF_ * 1536 * 2;
  const size_t NEEDED   = OFF_LIOU + SZ_LIOU;

  if (ws_size < NEEDED) {
    int n = 2 * NN_ * 512;
    fill_sentinel<<<(n + 255) / 256, 256, 0, stream>>>((float*)d_out, n);
    return;
  }

  char* ws = (char*)d_ws;
  unsigned short* HB    = (unsigned short*)(ws + OFF_HB);
  unsigned short* FB    = (unsigned short*)(ws + OFF_FB);
  unsigned short* WF    = (unsigned short*)(ws + OFF_WFm);
  unsigned short* UCAT2 = (unsigned short*)(ws + OFF_UC2);
  unsigned short* UFLR  = (unsigned short*)(ws + OFF_UFLR);
  unsigned short* WFB   = (unsigned short*)(ws + OFF_WFB);
  unsigned short* LIOU  = (unsigned short*)(ws + OFF_LIOU);
  unsigned short* IOU   = (unsigned short*)(ws + OFF_LIOU);

  prep_weights<<<9216, 256, 0, stream>>>(Wiou, Ul, Ur, Wf, Ufl, Ufr,
                                         UCAT2, UFLR, WFB);
  feat2bf<<<(NN_ * 64 + 255) / 256, 256, 0, stream>>>(feat, FB);
  {
    int nwgW = ((NINT_ + 127) / 128) * 4;      // 1600
    int nwgL = (NLEAF_ / 128) * 12;            // 4800
    pre_mm<<<nwgW + nwgL, 256, 0, stream>>>(FB, WFB, UCAT2, bfb, biou,
                                            WF, LIOU, nwgW, nwgL);
  }
  leaf_ew<<<(NLEAF_ * 128) / 256, 256, 0, stream>>>(LIOU, h_out, c_out, HB);

  for (int l = 1; l <= 10; ++l) {
    int shift = 10 - l;
    int P = TREES_ << shift;
    int start_l   = 2048 - (1 << (11 - l));
    int start_lm1 = 2048 - (1 << (12 - l));
    int nwg1 = ((2 * P + 127) / 128) * 8;
    int nwg2 = ((P + 127) / 128) * 12;
    lvl_gemm<<<nwg1 + nwg2, 256, 0, stream>>>(HB, FB, UFLR, UCAT2, WF, biou,
                                              c_out, h_out, IOU,
                                              P, shift, start_l, start_lm1,
                                              nwg1, nwg2);
    int g3b = (P * 128 + 255) / 256;
    g3_kernel<<<g3b, 256, 0, stream>>>(IOU, h_out, c_out, HB, P, shift, start_l);
  }
}